// Round 2
// baseline (342.740 us; speedup 1.0000x reference)
//
#include <hip/hip_runtime.h>

// BatchedNLM: per-neuron 2-layer GLU MLP.
//   state_trace (128,2048,32) f32, fc1_w (2048,32,256), fc1_b (2048,256),
//   fc2_w (2048,128,2), fc2_b (2048,2), T (1)  ->  out (128,2048) f32
//
// One block per neuron. 256 threads = 4 waves; wave w owns batches [32w,32w+32).
// GEMM1 via mfma_f32_16x16x32_bf16 (K=32 in a single MFMA, acc from 0).
// GLU1 pairs (h, h+128) = tiles (p, p+8): same lane, same acc reg -> register-only.
// fc2 (K=128, N=2) folded into the tile loop as per-lane partials + shfl_xor tree.
//
// R2: results gathered to LDS and written as one coalesced 512B row into
// out_t (2048,128) in d_ws; separate LDS-tiled transpose kernel produces
// out (128,2048). Removes the 4B/8KB-stride scatter that caused 82 MB of
// partial-line writebacks + 63 MB write-allocate fetches in R1.
// __launch_bounds__(256,8): grid is exactly 8 blocks/CU; let them all reside.

#define NN 2048

typedef __attribute__((ext_vector_type(8))) short short8;
typedef __attribute__((ext_vector_type(4))) float floatx4;

static __device__ __forceinline__ short f2bf(float f) {
    unsigned int u = __float_as_uint(f);
    u += 0x7FFFu + ((u >> 16) & 1u);   // RNE round to bf16
    return (short)(u >> 16);
}

static __device__ __forceinline__ float sigmoidf(float x) {
    return 1.0f / (1.0f + __expf(-x));
}

__global__ __launch_bounds__(256, 8)
void nlm_kernel(const float* __restrict__ st,
                const float* __restrict__ w1,
                const float* __restrict__ b1,
                const float* __restrict__ w2,
                const float* __restrict__ b2,
                const float* __restrict__ Tp,
                float* __restrict__ out_t)
{
    const int n = blockIdx.x;
    const int t = threadIdx.x;

    // Fragment-major B: [tile p (16)][lane (64)][j (8)] bf16 = 16 KB.
    __shared__ short ldsB[16 * 64 * 8];
    __shared__ float ldsO[128];

    // ---- Stage W1[n] (32x256 f32) -> bf16 fragment-major LDS ----
    // Thread t handles column h = t. Global reads coalesced (256 contiguous
    // floats per (k) iteration across the block).
    {
        const int h = t;
        const float* wp = w1 + (size_t)n * 8192 + h;
        const int base = ((h >> 4) * 512) + ((h & 15) * 8); // shorts
        #pragma unroll
        for (int q = 0; q < 4; ++q) {
            short8 s;
            #pragma unroll
            for (int j = 0; j < 8; ++j)
                s[j] = f2bf(wp[(q * 8 + j) * 256]);
            *(short8*)&ldsB[base + q * 128] = s;  // dense 1KB region: conflict-free
        }
    }

    const int lane = t & 63;
    const int wv   = t >> 6;      // wave 0..3
    const int m    = lane & 15;   // A row / C col
    const int quad = lane >> 4;   // k-quad / C row group

    // ---- A fragments: A[m][k] = state[b][n][k], k = quad*8 + j (contiguous) ----
    short8 afrag[2];
    #pragma unroll
    for (int bt = 0; bt < 2; ++bt) {
        const int b = wv * 32 + bt * 16 + m;
        const float* sp = st + (size_t)b * (NN * 32) + (size_t)n * 32 + quad * 8;
        floatx4 v0 = *(const floatx4*)sp;
        floatx4 v1 = *(const floatx4*)(sp + 4);
        short8 a;
        a[0] = f2bf(v0[0]); a[1] = f2bf(v0[1]); a[2] = f2bf(v0[2]); a[3] = f2bf(v0[3]);
        a[4] = f2bf(v1[0]); a[5] = f2bf(v1[1]); a[6] = f2bf(v1[2]); a[7] = f2bf(v1[3]);
        afrag[bt] = a;
    }

    __syncthreads();

    const float* b1p = b1 + n * 256;
    const float* w2p = w2 + n * 256;

    // fc2 partial sums: [bt][reg(row)][o]
    float pacc[2][4][2];
    #pragma unroll
    for (int bt = 0; bt < 2; ++bt)
        #pragma unroll
        for (int r = 0; r < 4; ++r)
            pacc[bt][r][0] = pacc[bt][r][1] = 0.0f;

    #pragma unroll
    for (int p = 0; p < 8; ++p) {
        // B fragments for tile p (h = m + 16p) and p+8 (h + 128)
        short8 bfA = *(short8*)&ldsB[(p * 64 + lane) * 8];
        short8 bfB = *(short8*)&ldsB[((p + 8) * 64 + lane) * 8];

        const int h = p * 16 + m;          // 0..127
        const float bias_a = b1p[h];
        const float bias_b = b1p[128 + h];
        const float w2a = w2p[h * 2 + 0];
        const float w2b = w2p[h * 2 + 1];

        #pragma unroll
        for (int bt = 0; bt < 2; ++bt) {
            floatx4 z = {0.0f, 0.0f, 0.0f, 0.0f};
            floatx4 xa = __builtin_amdgcn_mfma_f32_16x16x32_bf16(afrag[bt], bfA, z, 0, 0, 0);
            floatx4 xb = __builtin_amdgcn_mfma_f32_16x16x32_bf16(afrag[bt], bfB, z, 0, 0, 0);
            #pragma unroll
            for (int r = 0; r < 4; ++r) {
                float a   = xa[r] + bias_a;
                float g   = xb[r] + bias_b;
                float glu = a * sigmoidf(g);
                pacc[bt][r][0] += glu * w2a;
                pacc[bt][r][1] += glu * w2b;
            }
        }
    }

    // ---- Reduce fc2 partials across the 16 lanes of each quad (over h's col idx) ----
    const float bb0 = b2[n * 2 + 0];
    const float bb1 = b2[n * 2 + 1];
    const float invT = 1.0f / Tp[0];

    #pragma unroll
    for (int bt = 0; bt < 2; ++bt) {
        #pragma unroll
        for (int r = 0; r < 4; ++r) {
            float s0 = pacc[bt][r][0];
            float s1 = pacc[bt][r][1];
            s0 += __shfl_xor(s0, 1);  s1 += __shfl_xor(s1, 1);
            s0 += __shfl_xor(s0, 2);  s1 += __shfl_xor(s1, 2);
            s0 += __shfl_xor(s0, 4);  s1 += __shfl_xor(s1, 4);
            s0 += __shfl_xor(s0, 8);  s1 += __shfl_xor(s1, 8);
            if (m == 0) {
                const int b = wv * 32 + bt * 16 + quad * 4 + r;
                float x0 = s0 + bb0;
                float x1 = s1 + bb1;
                ldsO[b] = x0 * sigmoidf(x1) * invT;
            }
        }
    }

    __syncthreads();

    // One coalesced 512B row per block into out_t (2048,128).
    if (t < 128)
        out_t[(size_t)n * 128 + t] = ldsO[t];
}

// Transpose out_t (2048,128) -> out (128,2048). 64n x 128b tiles, 32 blocks.
__global__ __launch_bounds__(256)
void transpose_kernel(const float* __restrict__ out_t, float* __restrict__ out)
{
    __shared__ float tile[64][129];   // +1 pad: write-phase stride-129 reads
    const int t  = threadIdx.x;
    const int n0 = blockIdx.x * 64;

    // Load: 2 n-rows per iteration, fully coalesced (1 KB per instr).
    const int tx = t & 127;          // b
    const int ty = t >> 7;           // 0..1
    #pragma unroll
    for (int i = 0; i < 32; ++i) {
        const int nl = ty + i * 2;
        tile[nl][tx] = out_t[(size_t)(n0 + nl) * 128 + tx];
    }

    __syncthreads();

    // Store: coalesced 256B segments along n.
    const int nl = t & 63;
    const int bq = t >> 6;           // 0..3
    #pragma unroll
    for (int i = 0; i < 32; ++i) {
        const int b = bq * 32 + i;
        out[(size_t)b * NN + n0 + nl] = tile[nl][b];
    }
}

extern "C" void kernel_launch(void* const* d_in, const int* in_sizes, int n_in,
                              void* d_out, int out_size, void* d_ws, size_t ws_size,
                              hipStream_t stream) {
    const float* st = (const float*)d_in[0];
    const float* w1 = (const float*)d_in[1];
    const float* b1 = (const float*)d_in[2];
    const float* w2 = (const float*)d_in[3];
    const float* b2 = (const float*)d_in[4];
    const float* T  = (const float*)d_in[5];
    float* out   = (float*)d_out;
    float* out_t = (float*)d_ws;    // 2048*128*4 = 1 MB scratch

    nlm_kernel<<<dim3(NN), dim3(256), 0, stream>>>(st, w1, b1, w2, b2, T, out_t);
    transpose_kernel<<<dim3(NN / 64), dim3(256), 0, stream>>>(out_t, out);
}

// Round 3
// 190.646 us; speedup vs baseline: 1.7978x; 1.7978x over previous
//
#include <hip/hip_runtime.h>

// BatchedNLM: per-neuron 2-layer GLU MLP.
//   state_trace (128,2048,32) f32, fc1_w (2048,32,256), fc1_b (2048,256),
//   fc2_w (2048,128,2), fc2_b (2048,2), T (1)  ->  out (128,2048) f32
//
// One block per neuron. 256 threads = 4 waves; wave w owns batches [32w,32w+32).
// GEMM1 via mfma_f32_16x16x32_bf16 (K=32 in a single MFMA, acc from 0).
// GLU1 pairs (h, h+128) = tiles (p, p+8): same lane, same acc reg -> register-only.
// fc2 (K=128, N=2) folded into the tile loop as per-lane partials + shfl_xor tree.
//
// R2: coalesced 512B row into out_t (2048,128) in d_ws + transpose kernel
//     (removes R1's 4B/8KB-stride scatter: 82 MB writebacks + 63 MB RMW fetches).
// R3: __launch_bounds__(256,4) — (256,8) in R2 forced VGPR 64->32 and ~500 MB
//     of scratch spill traffic (WRITE_SIZE 275 MB). 64 VGPR already allows
//     8 blocks/CU by HW arithmetic; never cap below what the kernel needs.
//     Transpose re-tiled 32x32 -> 256 blocks (R2's 32 blocks used 12.5% of CUs).

#define NN 2048

typedef __attribute__((ext_vector_type(8))) short short8;
typedef __attribute__((ext_vector_type(4))) float floatx4;

static __device__ __forceinline__ short f2bf(float f) {
    unsigned int u = __float_as_uint(f);
    u += 0x7FFFu + ((u >> 16) & 1u);   // RNE round to bf16
    return (short)(u >> 16);
}

static __device__ __forceinline__ float sigmoidf(float x) {
    return 1.0f / (1.0f + __expf(-x));
}

__global__ __launch_bounds__(256, 4)
void nlm_kernel(const float* __restrict__ st,
                const float* __restrict__ w1,
                const float* __restrict__ b1,
                const float* __restrict__ w2,
                const float* __restrict__ b2,
                const float* __restrict__ Tp,
                float* __restrict__ out_t)
{
    const int n = blockIdx.x;
    const int t = threadIdx.x;

    // Fragment-major B: [tile p (16)][lane (64)][j (8)] bf16 = 16 KB.
    __shared__ short ldsB[16 * 64 * 8];
    __shared__ float ldsO[128];

    // ---- Stage W1[n] (32x256 f32) -> bf16 fragment-major LDS ----
    // Thread t handles column h = t. Global reads coalesced (256 contiguous
    // floats per (k) iteration across the block).
    {
        const int h = t;
        const float* wp = w1 + (size_t)n * 8192 + h;
        const int base = ((h >> 4) * 512) + ((h & 15) * 8); // shorts
        #pragma unroll
        for (int q = 0; q < 4; ++q) {
            short8 s;
            #pragma unroll
            for (int j = 0; j < 8; ++j)
                s[j] = f2bf(wp[(q * 8 + j) * 256]);
            *(short8*)&ldsB[base + q * 128] = s;  // dense 1KB region: conflict-free
        }
    }

    const int lane = t & 63;
    const int wv   = t >> 6;      // wave 0..3
    const int m    = lane & 15;   // A row / C col
    const int quad = lane >> 4;   // k-quad / C row group

    // ---- A fragments: A[m][k] = state[b][n][k], k = quad*8 + j (contiguous) ----
    short8 afrag[2];
    #pragma unroll
    for (int bt = 0; bt < 2; ++bt) {
        const int b = wv * 32 + bt * 16 + m;
        const float* sp = st + (size_t)b * (NN * 32) + (size_t)n * 32 + quad * 8;
        floatx4 v0 = *(const floatx4*)sp;
        floatx4 v1 = *(const floatx4*)(sp + 4);
        short8 a;
        a[0] = f2bf(v0[0]); a[1] = f2bf(v0[1]); a[2] = f2bf(v0[2]); a[3] = f2bf(v0[3]);
        a[4] = f2bf(v1[0]); a[5] = f2bf(v1[1]); a[6] = f2bf(v1[2]); a[7] = f2bf(v1[3]);
        afrag[bt] = a;
    }

    __syncthreads();

    const float* b1p = b1 + n * 256;
    const float* w2p = w2 + n * 256;

    // fc2 partial sums: [bt][reg(row)][o]
    float pacc[2][4][2];
    #pragma unroll
    for (int bt = 0; bt < 2; ++bt)
        #pragma unroll
        for (int r = 0; r < 4; ++r)
            pacc[bt][r][0] = pacc[bt][r][1] = 0.0f;

    #pragma unroll
    for (int p = 0; p < 8; ++p) {
        // B fragments for tile p (h = m + 16p) and p+8 (h + 128)
        short8 bfA = *(short8*)&ldsB[(p * 64 + lane) * 8];
        short8 bfB = *(short8*)&ldsB[((p + 8) * 64 + lane) * 8];

        const int h = p * 16 + m;          // 0..127
        const float bias_a = b1p[h];
        const float bias_b = b1p[128 + h];
        const float w2a = w2p[h * 2 + 0];
        const float w2b = w2p[h * 2 + 1];

        #pragma unroll
        for (int bt = 0; bt < 2; ++bt) {
            floatx4 z = {0.0f, 0.0f, 0.0f, 0.0f};
            floatx4 xa = __builtin_amdgcn_mfma_f32_16x16x32_bf16(afrag[bt], bfA, z, 0, 0, 0);
            floatx4 xb = __builtin_amdgcn_mfma_f32_16x16x32_bf16(afrag[bt], bfB, z, 0, 0, 0);
            #pragma unroll
            for (int r = 0; r < 4; ++r) {
                float a   = xa[r] + bias_a;
                float g   = xb[r] + bias_b;
                float glu = a * sigmoidf(g);
                pacc[bt][r][0] += glu * w2a;
                pacc[bt][r][1] += glu * w2b;
            }
        }
    }

    // ---- Reduce fc2 partials across the 16 lanes of each quad (over h's col idx) ----
    const float bb0 = b2[n * 2 + 0];
    const float bb1 = b2[n * 2 + 1];
    const float invT = 1.0f / Tp[0];

    #pragma unroll
    for (int bt = 0; bt < 2; ++bt) {
        #pragma unroll
        for (int r = 0; r < 4; ++r) {
            float s0 = pacc[bt][r][0];
            float s1 = pacc[bt][r][1];
            s0 += __shfl_xor(s0, 1);  s1 += __shfl_xor(s1, 1);
            s0 += __shfl_xor(s0, 2);  s1 += __shfl_xor(s1, 2);
            s0 += __shfl_xor(s0, 4);  s1 += __shfl_xor(s1, 4);
            s0 += __shfl_xor(s0, 8);  s1 += __shfl_xor(s1, 8);
            if (m == 0) {
                const int b = wv * 32 + bt * 16 + quad * 4 + r;
                float x0 = s0 + bb0;
                float x1 = s1 + bb1;
                ldsO[b] = x0 * sigmoidf(x1) * invT;
            }
        }
    }

    __syncthreads();

    // One coalesced 512B row per block into out_t (2048,128).
    if (t < 128)
        out_t[(size_t)n * 128 + t] = ldsO[t];
}

// Transpose out_t (2048,128) -> out (128,2048). 32x32 tiles, 256 blocks.
__global__ __launch_bounds__(256)
void transpose_kernel(const float* __restrict__ out_t, float* __restrict__ out)
{
    __shared__ float tile[32][33];
    const int t    = threadIdx.x;
    const int bidx = blockIdx.x;           // 0..255
    const int n0   = (bidx & 63) * 32;     // 64 n-tiles
    const int b0   = (bidx >> 6) * 32;     // 4 b-tiles

    const int tx = t & 31;
    const int ty = t >> 5;                 // 0..7

    #pragma unroll
    for (int i = 0; i < 4; ++i) {
        const int nl = ty + i * 8;
        tile[nl][tx] = out_t[(size_t)(n0 + nl) * 128 + b0 + tx];
    }

    __syncthreads();

    #pragma unroll
    for (int i = 0; i < 4; ++i) {
        const int bl = ty + i * 8;
        // LDS read tile[tx][bl]: addr = 33*tx + bl -> bank = tx (distinct
        // per 32 lanes, 2-way across the wave = free).
        out[(size_t)(b0 + bl) * NN + n0 + tx] = tile[tx][bl];
    }
}

extern "C" void kernel_launch(void* const* d_in, const int* in_sizes, int n_in,
                              void* d_out, int out_size, void* d_ws, size_t ws_size,
                              hipStream_t stream) {
    const float* st = (const float*)d_in[0];
    const float* w1 = (const float*)d_in[1];
    const float* b1 = (const float*)d_in[2];
    const float* w2 = (const float*)d_in[3];
    const float* b2 = (const float*)d_in[4];
    const float* T  = (const float*)d_in[5];
    float* out   = (float*)d_out;
    float* out_t = (float*)d_ws;    // 2048*128*4 = 1 MB scratch

    nlm_kernel<<<dim3(NN), dim3(256), 0, stream>>>(st, w1, b1, w2, b2, T, out_t);
    transpose_kernel<<<dim3(256), dim3(256), 0, stream>>>(out_t, out);
}